// Round 11
// baseline (220.987 us; speedup 1.0000x reference)
//
#include <hip/hip_runtime.h>
#include <math.h>

// WildcatPool2d: x[32,64,64,512] fp32 -> out[32,512] fp32
// out[b,c] = mean(top20 over 4096 spatial) + mean(bottom20 over 4096 spatial)
//
// Round 11: filter-then-select. Ten sort-based variants all landed 70-90us;
// the selection machinery (~28 ops/elem) is inseparable from the stream.
// New algorithm:
//  K0: zero per-(b,c) counters.
//  K1: pure stream: float4 load, |x|>TAU compare, rare atomic append of
//      candidates (exp ~83/channel, cap 152). ~0.3 VALU ops/elem.
//  K2: wave per (b,c): exact 20th-largest via 32-bit binary search on
//      ordered-int float bits over candidates (ballot+popc counts, order
//      independent); sum of top-20 incl. duplicate handling, in double.
//      Fallback (count<20 or >cap, prob ~1e-5, never wrong): exact
//      whole-channel bit-search.
// Exactness: if count(x>TAU) >= 20 then top20 subset of candidates; the
// bit-search computes the exact 20th value and mean. Same for bottom via
// negation. Undercount/overflow always detected via the true counter.

constexpr int   CH  = 512;
constexpr int   NR  = 4096;
constexpr int   NBC = 32 * CH;       // 16384 (b,c) pairs
constexpr int   CAP = 152;
constexpr float TAU = 2.05f;
constexpr size_t WS_NEED = (size_t)NBC * CAP * 2 * 4 + (size_t)NBC * 2 * 4; // 20.05 MB

__device__ __forceinline__ unsigned enc(float f) {
  unsigned u = __float_as_uint(f);
  return (u >> 31) ? ~u : (u | 0x80000000u);
}
__device__ __forceinline__ float dec(unsigned e) {
  unsigned b = (e & 0x80000000u) ? (e ^ 0x80000000u) : ~e;
  return __uint_as_float(b);
}

// ---------------- K0: zero the 2*16384 counters ----------------
__global__ __launch_bounds__(256)
void wc_zero(int* __restrict__ cnts) {
  int i = blockIdx.x * 256 + threadIdx.x;
  if (i < 2 * NBC) cnts[i] = 0;
}

// ---------------- K1: stream + filter + append ----------------
__device__ __forceinline__ void appendv(float f, int bc, float* __restrict__ cand,
                                        int* __restrict__ cnt) {
  if (f > TAU) {
    int idx = atomicAdd(cnt + bc, 1);
    if (idx < CAP) cand[(size_t)bc * CAP + idx] = f;
  }
}

__global__ __launch_bounds__(256)
void wc_filter(const float4* __restrict__ x4,
               float* __restrict__ cand_hi, float* __restrict__ cand_lo,
               int* __restrict__ cnt_hi, int* __restrict__ cnt_lo) {
  const int blk  = blockIdx.x;        // 2048 blocks
  const int b    = blk >> 6;          // 64 blocks per batch image
  const int part = blk & 63;          // 64 rows per part
  const int t    = threadIdx.x;

  // c4 = (t & 127): channel-quad is loop-invariant (8192, 256 are mult of 128)
  const int bcb = b * CH + (t & 127) * 4;
  const float4* p = x4 + (size_t)b * (NR * CH / 4) + part * 8192 + t;

  #pragma unroll 4
  for (int i = 0; i < 32; ++i) {
    float4 v = p[(size_t)i * 256];
    appendv( v.x, bcb + 0, cand_hi, cnt_hi);
    appendv( v.y, bcb + 1, cand_hi, cnt_hi);
    appendv( v.z, bcb + 2, cand_hi, cnt_hi);
    appendv( v.w, bcb + 3, cand_hi, cnt_hi);
    appendv(-v.x, bcb + 0, cand_lo, cnt_lo);
    appendv(-v.y, bcb + 1, cand_lo, cnt_lo);
    appendv(-v.z, bcb + 2, cand_lo, cnt_lo);
    appendv(-v.w, bcb + 3, cand_lo, cnt_lo);
  }
}

// ---------------- K2: exact top-20 mean per (b,c), wave per bc ----------------
// returns mean(top20) of the positive-side multiset this wave holds/streams
__device__ float top20_mean_cand(const float* __restrict__ candp, int cnt, int lane) {
  float f0 = 0.f, f1 = 0.f, f2 = 0.f;
  unsigned u0 = 0, u1 = 0, u2 = 0;
  if (lane < cnt)       { f0 = candp[lane];       u0 = enc(f0); }
  if (64 + lane < cnt)  { f1 = candp[64 + lane];  u1 = enc(f1); }
  if (128 + lane < cnt) { f2 = candp[128 + lane]; u2 = enc(f2); }

  unsigned cur = 0;
  #pragma unroll 1
  for (int bit = 31; bit >= 0; --bit) {
    unsigned th = cur | (1u << bit);
    int c = __popcll(__ballot(u0 >= th)) + __popcll(__ballot(u1 >= th)) +
            __popcll(__ballot(u2 >= th));
    if (c >= 20) cur = th;
  }
  int ngt = __popcll(__ballot(u0 > cur)) + __popcll(__ballot(u1 > cur)) +
            __popcll(__ballot(u2 > cur));
  double s = 0.0;
  if (u0 > cur) s += (double)f0;
  if (u1 > cur) s += (double)f1;
  if (u2 > cur) s += (double)f2;
  #pragma unroll
  for (int m = 1; m < 64; m <<= 1) s += __shfl_xor(s, m, 64);
  s += (double)(20 - ngt) * (double)dec(cur);
  return (float)(s * (1.0 / 20.0));
}

// exact fallback: stream the whole channel (values pre-multiplied by sgn)
__device__ float top20_mean_full(const float* __restrict__ chp, float sgn, int lane) {
  unsigned cur = 0;
  #pragma unroll 1
  for (int bit = 31; bit >= 0; --bit) {
    unsigned th = cur | (1u << bit);
    int c = 0;
    #pragma unroll 1
    for (int r = 0; r < 64; ++r) {
      float f = sgn * chp[(size_t)(r * 64 + lane) * CH];
      c += __popcll(__ballot(enc(f) >= th));
    }
    if (c >= 20) cur = th;
  }
  double s = 0.0;
  int ngt = 0;
  #pragma unroll 1
  for (int r = 0; r < 64; ++r) {
    float f = sgn * chp[(size_t)(r * 64 + lane) * CH];
    unsigned u = enc(f);
    if (u > cur) s += (double)f;
    ngt += __popcll(__ballot(u > cur));
  }
  #pragma unroll
  for (int m = 1; m < 64; m <<= 1) s += __shfl_xor(s, m, 64);
  s += (double)(20 - ngt) * (double)dec(cur);
  return (float)(s * (1.0 / 20.0));
}

__global__ __launch_bounds__(256)
void wc_select(const float* __restrict__ x,
               const float* __restrict__ cand_hi, const float* __restrict__ cand_lo,
               const int* __restrict__ cnt_hi, const int* __restrict__ cnt_lo,
               float* __restrict__ out) {
  const int wid  = blockIdx.x * 4 + (threadIdx.x >> 6);   // 16384 waves
  const int lane = threadIdx.x & 63;
  const int bc   = wid;
  const int b    = bc >> 9;
  const int c    = bc & (CH - 1);
  const float* chp = x + (size_t)b * NR * CH + c;

  int ch_ = cnt_hi[bc];
  float mean_hi = (ch_ >= 20 && ch_ <= CAP)
      ? top20_mean_cand(cand_hi + (size_t)bc * CAP, ch_, lane)
      : top20_mean_full(chp, 1.0f, lane);

  int cl_ = cnt_lo[bc];
  float mean_lo_neg = (cl_ >= 20 && cl_ <= CAP)
      ? top20_mean_cand(cand_lo + (size_t)bc * CAP, cl_, lane)
      : top20_mean_full(chp, -1.0f, lane);

  if (lane == 0) out[bc] = mean_hi - mean_lo_neg;   // bottom mean = -top(-x)
}

// ---------------- fallback single kernel (round-4 champion) if ws too small --
__device__ __forceinline__ void ce_desc(float& a, float& b) {
  float hi = fmaxf(a, b); float lo = fminf(a, b); a = hi; b = lo;
}
__device__ __forceinline__ void ce_asc(float& a, float& b) {
  float lo = fminf(a, b); float hi = fmaxf(a, b); a = lo; b = hi;
}
__device__ __forceinline__ void sort32_desc(float* v) {
  #pragma unroll
  for (int k = 2; k <= 32; k <<= 1)
    #pragma unroll
    for (int j = k >> 1; j > 0; j >>= 1)
      #pragma unroll
      for (int i = 0; i < 32; ++i) {
        int l = i ^ j;
        if (l > i) { if ((i & k) == 0) ce_desc(v[i], v[l]); else ce_asc(v[i], v[l]); }
      }
}
__device__ __forceinline__ void clean32_desc(float* v) {
  #pragma unroll
  for (int j = 16; j > 0; j >>= 1)
    #pragma unroll
    for (int i = 0; i < 32; ++i) { int l = i ^ j; if (l > i) ce_desc(v[i], v[l]); }
}
__device__ __forceinline__ void clean32_asc(float* v) {
  #pragma unroll
  for (int j = 16; j > 0; j >>= 1)
    #pragma unroll
    for (int i = 0; i < 32; ++i) { int l = i ^ j; if (l > i) ce_asc(v[i], v[l]); }
}
__device__ __forceinline__ void merge_top_fb(float* top, const float* d) {
  #pragma unroll
  for (int i = 0; i < 32; ++i) top[i] = fmaxf(top[i], d[31 - i]);
  clean32_desc(top);
}
__device__ __forceinline__ void merge_bot_fb(float* bot, const float* d) {
  #pragma unroll
  for (int i = 0; i < 32; ++i) bot[i] = fminf(bot[i], d[i]);
  clean32_asc(bot);
}
__device__ __forceinline__ void load_batch_fb(const float* __restrict__ p0, int t, float* v) {
  const float* p = p0 + (size_t)t * (64 * CH);
  #pragma unroll
  for (int u = 0; u < 32; ++u) v[u] = p[(size_t)(u * 2 * CH)];
}
__global__ __launch_bounds__(256, 1)
void wildcat_fallback(const float* __restrict__ x, float* __restrict__ out) {
  const int b     = blockIdx.x >> 4;
  const int cbase = (blockIdx.x & 15) << 5;
  const int w     = threadIdx.x >> 6;
  const int lane  = threadIdx.x & 63;
  const int c     = cbase + (lane & 31);
  const int rpar  = lane >> 5;
  const float* p0 = x + ((size_t)(b * NR + w * 1024 + rpar)) * CH + c;

  float top[32], bot[32], vA[32], vB[32];
  load_batch_fb(p0, 0, vA);
  load_batch_fb(p0, 1, vB);
  __builtin_amdgcn_sched_barrier(0);
  sort32_desc(vA);
  #pragma unroll
  for (int i = 0; i < 32; ++i) { top[i] = vA[i]; bot[i] = vA[31 - i]; }
  for (int tp = 0; tp < 7; ++tp) {
    load_batch_fb(p0, 2 * tp + 2, vA);
    __builtin_amdgcn_sched_barrier(0);
    sort32_desc(vB); merge_top_fb(top, vB); merge_bot_fb(bot, vB);
    load_batch_fb(p0, 2 * tp + 3, vB);
    __builtin_amdgcn_sched_barrier(0);
    sort32_desc(vA); merge_top_fb(top, vA); merge_bot_fb(bot, vA);
  }
  sort32_desc(vB); merge_top_fb(top, vB); merge_bot_fb(bot, vB);
  {
    float pt[32], pb[32];
    #pragma unroll
    for (int i = 0; i < 32; ++i) pt[i] = __shfl_xor(top[i], 32, 64);
    #pragma unroll
    for (int i = 0; i < 32; ++i) pb[i] = __shfl_xor(bot[i], 32, 64);
    #pragma unroll
    for (int i = 0; i < 32; ++i) top[i] = fmaxf(top[i], pt[31 - i]);
    clean32_desc(top);
    #pragma unroll
    for (int i = 0; i < 32; ++i) bot[i] = fminf(bot[i], pb[31 - i]);
    clean32_asc(bot);
  }
  __shared__ float lds[2 * 32 * 65];
  #pragma unroll
  for (int hw = 2; hw >= 1; hw >>= 1) {
    __syncthreads();
    if (w >= hw && w < 2 * hw && lane < 32) {
      float* dst = &lds[((w - hw) * 32 + lane) * 65];
      #pragma unroll
      for (int i = 0; i < 32; ++i) { dst[i] = top[i]; dst[32 + i] = bot[i]; }
    }
    __syncthreads();
    if (w < hw && lane < 32) {
      const float* src = &lds[(w * 32 + lane) * 65];
      #pragma unroll
      for (int i = 0; i < 16; ++i) {
        float a = src[31 - i], bb = src[i];
        top[i] = fmaxf(top[i], a); top[31 - i] = fmaxf(top[31 - i], bb);
      }
      clean32_desc(top);
      #pragma unroll
      for (int i = 0; i < 16; ++i) {
        float a = src[32 + 31 - i], bb = src[32 + i];
        bot[i] = fminf(bot[i], a); bot[31 - i] = fminf(bot[31 - i], bb);
      }
      clean32_asc(bot);
    }
  }
  if (w == 0 && lane < 32) {
    float s = 0.f;
    #pragma unroll
    for (int i = 0; i < 20; ++i) s += top[i] + bot[i];
    out[b * CH + cbase + lane] = s * (1.0f / 20.0f);
  }
}

extern "C" void kernel_launch(void* const* d_in, const int* in_sizes, int n_in,
                              void* d_out, int out_size, void* d_ws, size_t ws_size,
                              hipStream_t stream) {
  const float* x = (const float*)d_in[0];
  float* out = (float*)d_out;
  if (ws_size >= WS_NEED) {
    float* cand_hi = (float*)d_ws;
    float* cand_lo = cand_hi + (size_t)NBC * CAP;
    int*   cnt_hi  = (int*)(cand_lo + (size_t)NBC * CAP);
    int*   cnt_lo  = cnt_hi + NBC;
    hipLaunchKernelGGL(wc_zero,   dim3(128),  dim3(256), 0, stream, cnt_hi);
    hipLaunchKernelGGL(wc_filter, dim3(2048), dim3(256), 0, stream,
                       (const float4*)x, cand_hi, cand_lo, cnt_hi, cnt_lo);
    hipLaunchKernelGGL(wc_select, dim3(4096), dim3(256), 0, stream,
                       x, cand_hi, cand_lo, cnt_hi, cnt_lo, out);
  } else {
    hipLaunchKernelGGL(wildcat_fallback, dim3(512), dim3(256), 0, stream, x, out);
  }
}

// Round 12
// 72.987 us; speedup vs baseline: 3.0277x; 3.0277x over previous
//
#include <hip/hip_runtime.h>
#include <math.h>

// WildcatPool2d: x[32,64,64,512] fp32 -> out[32,512] fp32
// out[b,c] = mean(top20 over 4096 spatial) + mean(bottom20 over 4096 spatial)
//
// Round 12: minimal-delta A/B on the R4 champion (70.8us): loads become
// NON-TEMPORAL (nt flag, bypass L2/LLC retention). R11's profile showed
// FETCH=131MB for a 268MB input -> ~half the stream is LLC-served (input
// almost fits the 256MB IC and thrashes it). Hypothesis: the LLC-mix path
// is what caps reads at ~3.8 TB/s; nt-streaming should run the whole read
// at the HBM rate the 7 TB/s fill kernels demonstrate.
// Everything else is byte-identical to R4.

constexpr int CH = 512;
constexpr int NR = 4096;
constexpr int K  = 20;

__device__ __forceinline__ void ce_desc(float& a, float& b) {
  float hi = fmaxf(a, b);
  float lo = fminf(a, b);
  a = hi; b = lo;
}
__device__ __forceinline__ void ce_asc(float& a, float& b) {
  float lo = fminf(a, b);
  float hi = fmaxf(a, b);
  a = lo; b = hi;
}

// full bitonic sort of 32 registers, descending
__device__ __forceinline__ void sort32_desc(float* v) {
  #pragma unroll
  for (int k = 2; k <= 32; k <<= 1) {
    #pragma unroll
    for (int j = k >> 1; j > 0; j >>= 1) {
      #pragma unroll
      for (int i = 0; i < 32; ++i) {
        int l = i ^ j;
        if (l > i) {
          if ((i & k) == 0) ce_desc(v[i], v[l]);
          else              ce_asc(v[i], v[l]);
        }
      }
    }
  }
}
__device__ __forceinline__ void clean32_desc(float* v) {
  #pragma unroll
  for (int j = 16; j > 0; j >>= 1) {
    #pragma unroll
    for (int i = 0; i < 32; ++i) {
      int l = i ^ j;
      if (l > i) ce_desc(v[i], v[l]);
    }
  }
}
__device__ __forceinline__ void clean32_asc(float* v) {
  #pragma unroll
  for (int j = 16; j > 0; j >>= 1) {
    #pragma unroll
    for (int i = 0; i < 32; ++i) {
      int l = i ^ j;
      if (l > i) ce_asc(v[i], v[l]);
    }
  }
}
// merge a descending-sorted 32-array d into top (descending, keeps 32 largest)
__device__ __forceinline__ void merge_top(float* top, const float* d) {
  #pragma unroll
  for (int i = 0; i < 32; ++i) top[i] = fmaxf(top[i], d[31 - i]);
  clean32_desc(top);
}
// merge a descending-sorted 32-array d into bot (ascending, keeps 32 smallest)
__device__ __forceinline__ void merge_bot(float* bot, const float* d) {
  #pragma unroll
  for (int i = 0; i < 32; ++i) bot[i] = fminf(bot[i], d[i]);
  clean32_asc(bot);
}
__device__ __forceinline__ void process_batch(float* v, float* top, float* bot) {
  sort32_desc(v);
  merge_top(top, v);
  merge_bot(bot, v);
}

// load batch t (32 elems, stride 2 rows) into v — NON-TEMPORAL (the only
// change vs round 4)
__device__ __forceinline__ void load_batch(const float* __restrict__ p0, int t, float* v) {
  const float* p = p0 + (size_t)t * (64 * CH);
  #pragma unroll
  for (int u = 0; u < 32; ++u)
    v[u] = __builtin_nontemporal_load(&p[(size_t)(u * 2 * CH)]);
}

__global__ __launch_bounds__(256, 1)
void wildcat_topk_kernel(const float* __restrict__ x, float* __restrict__ out) {
  const int b     = blockIdx.x >> 4;           // 32 batches
  const int cbase = (blockIdx.x & 15) << 5;    // 16 channel groups of 32
  const int w     = threadIdx.x >> 6;          // wave 0..3
  const int lane  = threadIdx.x & 63;
  const int c     = cbase + (lane & 31);
  const int rpar  = lane >> 5;                 // row parity 0/1

  // wave w owns rows [w*1024, (w+1)*1024); lane parity splits even/odd rows.
  const float* p0 = x + ((size_t)(b * NR + w * 1024 + rpar)) * CH + c;

  float top[32], bot[32], vA[32], vB[32];

  // prologue: batch 0 -> vA, batch 1 -> vB (both in flight)
  load_batch(p0, 0, vA);
  load_batch(p0, 1, vB);
  __builtin_amdgcn_sched_barrier(0);   // pin: both prefetches issued before any sort

  // batch 0 initializes top/bot directly (saves one merge)
  sort32_desc(vA);
  #pragma unroll
  for (int i = 0; i < 32; ++i) { top[i] = vA[i]; bot[i] = vA[31 - i]; }

  // batches 1..14 in 7 ping-pong pairs; batch 15 in the epilogue.
  for (int tp = 0; tp < 7; ++tp) {
    load_batch(p0, 2 * tp + 2, vA);    // prefetch (must overlap sort of vB)
    __builtin_amdgcn_sched_barrier(0); // loads may not sink below this point
    process_batch(vB, top, bot);       // batch 2tp+1

    load_batch(p0, 2 * tp + 3, vB);    // prefetch (must overlap sort of vA)
    __builtin_amdgcn_sched_barrier(0);
    process_batch(vA, top, bot);       // batch 2tp+2
  }
  process_batch(vB, top, bot);         // batch 15

  // --- intra-wave merge: lane l <-> l+32 (same channel, other row parity) ---
  {
    float pt[32], pb[32];
    #pragma unroll
    for (int i = 0; i < 32; ++i) pt[i] = __shfl_xor(top[i], 32, 64);
    #pragma unroll
    for (int i = 0; i < 32; ++i) pb[i] = __shfl_xor(bot[i], 32, 64);
    #pragma unroll
    for (int i = 0; i < 32; ++i) top[i] = fmaxf(top[i], pt[31 - i]);
    clean32_desc(top);
    #pragma unroll
    for (int i = 0; i < 32; ++i) bot[i] = fminf(bot[i], pb[31 - i]);
    clean32_asc(bot);
  }

  // --- cross-wave tree merge via LDS: 4 -> 2 -> 1 ---
  __shared__ float lds[2 * 32 * 64];   // 16 KB

  #pragma unroll
  for (int half = 2; half >= 1; half >>= 1) {
    __syncthreads();
    if (w >= half && w < 2 * half && lane < 32) {
      float* dst = &lds[((w - half) * 32 + lane) * 64];
      #pragma unroll
      for (int i = 0; i < 32; ++i) { dst[i] = top[i]; dst[32 + i] = bot[i]; }
    }
    __syncthreads();
    if (w < half && lane < 32) {
      const float* src = &lds[(w * 32 + lane) * 64];
      float pt[32], pb[32];
      #pragma unroll
      for (int i = 0; i < 32; ++i) { pt[i] = src[i]; pb[i] = src[32 + i]; }
      #pragma unroll
      for (int i = 0; i < 32; ++i) top[i] = fmaxf(top[i], pt[31 - i]);
      clean32_desc(top);
      #pragma unroll
      for (int i = 0; i < 32; ++i) bot[i] = fminf(bot[i], pb[31 - i]);
      clean32_asc(bot);
    }
  }

  if (w == 0 && lane < 32) {
    float s = 0.f;
    #pragma unroll
    for (int i = 0; i < K; ++i) s += top[i] + bot[i];
    out[b * CH + cbase + lane] = s * (1.0f / K);
  }
}

extern "C" void kernel_launch(void* const* d_in, const int* in_sizes, int n_in,
                              void* d_out, int out_size, void* d_ws, size_t ws_size,
                              hipStream_t stream) {
  const float* x = (const float*)d_in[0];
  float* out = (float*)d_out;
  // grid: 32 (B) * 16 channel-groups = 512 blocks, 256 threads each
  // (2 blocks/CU, all co-resident)
  hipLaunchKernelGGL(wildcat_topk_kernel, dim3(512), dim3(256), 0, stream, x, out);
}